// Round 23
// baseline (79.692 us; speedup 1.0000x reference)
//
#include <hip/hip_runtime.h>
#include <math.h>

// Problem constants (from reference)
#define N_Q 4096
#define M_K 8192
#define D_DIM 512
#define P_IDX 4
#define INV_TEMP 10.0f

#define NCHUNK 128          // 8192 cols / 64-col chunks (one per bx block)

typedef __attribute__((ext_vector_type(8))) _Float16 f16x8;
typedef __attribute__((ext_vector_type(16))) float f32x16;

// ---------------------------------------------------------------------------
// Pack fp32 row-major [nrows][512] into MFMA-fragment-ordered fp16 (Q and K
// fused in one launch; Q pre-scaled by INV_TEMP).
// 16B chunk c = (rb*32+ks)*64 + lane holds row rb*32+(lane&31),
// k-octet (ks*2 + lane>>5).  A wave's 32x32x16 fragment for (rb, ks) is the
// contiguous 1 KB at chunk (rb*32+ks)*64 -> perfectly coalesced stream.
// ---------------------------------------------------------------------------
__global__ __launch_bounds__(256)
void pack_f16(const float* __restrict__ Q, const float* __restrict__ K,
              _Float16* __restrict__ Pq, _Float16* __restrict__ Pk,
              int qunits, int totunits)
{
    const int wunit = blockIdx.x * 4 + (threadIdx.x >> 6);
    if (wunit >= totunits) return;
    const bool isq = (wunit < qunits);
    const int u = isq ? wunit : wunit - qunits;
    const float* X = isq ? Q : K;
    _Float16* P = isq ? Pq : Pk;
    const float scale = isq ? INV_TEMP : 1.0f;
    const int rb = u >> 5, ks = u & 31;
    const int lane = threadIdx.x & 63;
    const int hi = lane >> 5, lx = lane & 31;
    const int row = rb * 32 + lx;
    const float4* src = (const float4*)(X + (size_t)row * D_DIM + ks * 16 + hi * 8);
    float4 v0 = src[0], v1 = src[1];
    f16x8 o;
    o[0] = (_Float16)(v0.x * scale); o[1] = (_Float16)(v0.y * scale);
    o[2] = (_Float16)(v0.z * scale); o[3] = (_Float16)(v0.w * scale);
    o[4] = (_Float16)(v1.x * scale); o[5] = (_Float16)(v1.y * scale);
    o[6] = (_Float16)(v1.z * scale); o[7] = (_Float16)(v1.w * scale);
    ((f16x8*)P)[(size_t)u * 64 + lane] = o;
}

__device__ __forceinline__ void gload16(const void* g, const void* l) {
    __builtin_amdgcn_global_load_lds(
        (const __attribute__((address_space(1))) unsigned int*)g,
        (__attribute__((address_space(3))) unsigned int*)l, 16, 0, 0);
}

// ---------------------------------------------------------------------------
// K-panel-resident swapped fp16 MFMA GEMM: scores^T = MFMA(K, Q).
// Block stages its ENTIRE 64-K-row panel (64 KB, packed chunk order ->
// linear gload_lds) into LDS ONCE + one barrier; then loops over 4 Q-tiles
// streaming B from L2 with the proven depth-4 ring (no further barriers).
// Waves partition Q disjointly (4 waves x 32 rows) -> B has ZERO duplicate
// reads; A reads come from LDS (conflict-free 16B/lane).  L2 traffic drops
// 1.05 GB -> ~0.59 GB vs the pure streaming kernel.
// Lane axis = Q-row, reg pattern = K-col -> in-lane epilogue + shfl_xor(32)
// hi-merge (R18-verified); chunk = bx (64 K-cols), NCHUNK = 128.
// Grid (128 bx, 8 by-slices), block 256 (4 waves), 2 blocks/CU (64 KB LDS).
// ---------------------------------------------------------------------------
__global__ __launch_bounds__(256)
void scores_mfma(const _Float16* __restrict__ Qp, const _Float16* __restrict__ Kp,
                 const int* __restrict__ ign, float4* __restrict__ part)
{
    __shared__ __align__(16) _Float16 As[32768];   // 64 KB: 4096 x 16B chunks

    const int tid = threadIdx.x;          // 0..255
    const int lane = tid & 63;
    const int w = tid >> 6;               // 0..3  (Q sub-tile owner)
    const int hi = lane >> 5, lx = lane & 31;
    const int bx = blockIdx.x;            // K-tile (64 rows), 0..127
    const int slice = blockIdx.y;         // 0..7 -> by = slice*4 + t

    const f16x8* Kp8 = (const f16x8*)Kp;
    const f16x8* Qp8 = (const f16x8*)Qp;
    f16x8* As8 = (f16x8*)As;

    // ---- stage the K panel once: global chunks [bx*4096, bx*4096+4096) ----
    {
        const f16x8* src = Kp8 + (size_t)bx * 4096;
#pragma unroll
        for (int it = 0; it < 16; ++it)
            gload16(src + it * 256 + tid, As8 + it * 256 + tid);
    }
    __syncthreads();    // drains vmcnt + all waves see the panel (only barrier)

    // B stream for by = slice*4 + 0: qrb = by*4 + w
    int qrb = (slice * 4) * 4 + w;
    const f16x8* Bp = Qp8 + (size_t)qrb * 2048 + lane;   // 32 chunks of 1 KB
    f16x8 bR = Bp[0], bS = Bp[64], bT = Bp[128], bU = Bp[192];

    for (int t = 0; t < 4; ++t) {
        const int by = slice * 4 + t;
        f32x16 acc0 = (f32x16)0.f, acc1 = (f32x16)0.f;

#pragma unroll
        for (int ks = 0; ks < 32; ks += 4) {
            // --- ks: consume bR ---
            {
                f16x8 a0 = As8[(ks) * 64 + lane];
                f16x8 a1 = As8[(32 + ks) * 64 + lane];
                __builtin_amdgcn_s_setprio(1);
                acc0 = __builtin_amdgcn_mfma_f32_32x32x16_f16(a0, bR, acc0, 0, 0, 0);
                acc1 = __builtin_amdgcn_mfma_f32_32x32x16_f16(a1, bR, acc1, 0, 0, 0);
                __builtin_amdgcn_s_setprio(0);
            }
            if (ks + 4 < 32) bR = Bp[(ks + 4) * 64];
            // --- ks+1: consume bS ---
            {
                f16x8 a0 = As8[(ks + 1) * 64 + lane];
                f16x8 a1 = As8[(33 + ks) * 64 + lane];
                __builtin_amdgcn_s_setprio(1);
                acc0 = __builtin_amdgcn_mfma_f32_32x32x16_f16(a0, bS, acc0, 0, 0, 0);
                acc1 = __builtin_amdgcn_mfma_f32_32x32x16_f16(a1, bS, acc1, 0, 0, 0);
                __builtin_amdgcn_s_setprio(0);
            }
            if (ks + 5 < 32) bS = Bp[(ks + 5) * 64];
            // --- ks+2: consume bT ---
            {
                f16x8 a0 = As8[(ks + 2) * 64 + lane];
                f16x8 a1 = As8[(34 + ks) * 64 + lane];
                __builtin_amdgcn_s_setprio(1);
                acc0 = __builtin_amdgcn_mfma_f32_32x32x16_f16(a0, bT, acc0, 0, 0, 0);
                acc1 = __builtin_amdgcn_mfma_f32_32x32x16_f16(a1, bT, acc1, 0, 0, 0);
                __builtin_amdgcn_s_setprio(0);
            }
            if (ks + 6 < 32) bT = Bp[(ks + 6) * 64];
            // --- ks+3: consume bU ---
            {
                f16x8 a0 = As8[(ks + 3) * 64 + lane];
                f16x8 a1 = As8[(35 + ks) * 64 + lane];
                __builtin_amdgcn_s_setprio(1);
                acc0 = __builtin_amdgcn_mfma_f32_32x32x16_f16(a0, bU, acc0, 0, 0, 0);
                acc1 = __builtin_amdgcn_mfma_f32_32x32x16_f16(a1, bU, acc1, 0, 0, 0);
                __builtin_amdgcn_s_setprio(0);
            }
            if (ks + 7 < 32) bU = Bp[(ks + 7) * 64];
        }

        // issue next by's B prologue FIRST -> latency hides under epilogue
        const f16x8* Bpn = Bp + 8192;     // qrb += 4
        if (t < 3) { bR = Bpn[0]; bS = Bpn[64]; bT = Bpn[128]; bU = Bpn[192]; }
        Bp = Bpn;

        // Epilogue (in-lane + hi-merge):
        //   acc{i}[r] = score(qrow = by*128 + w*32 + lx,
        //                     kcol = bx*64 + i*32 + (r&3)+8*(r>>2)+4*hi)
        const int qrow = by * 128 + w * 32 + lx;
        const int kbase = bx * 64 + 4 * hi;
        const int4 ig = ((const int4*)ign)[qrow];
        float bm = -INFINITY; int bi = 0x7fffffff;
#pragma unroll
        for (int r = 0; r < 16; ++r) {
            const int col = kbase + (r & 3) + 8 * (r >> 2);
            float x = acc0[r];
            if (col == ig.x || col == ig.y || col == ig.z || col == ig.w)
                x = -INFINITY;
            acc0[r] = x;
            if (x > bm || (x == bm && col < bi)) { bm = x; bi = col; }
        }
#pragma unroll
        for (int r = 0; r < 16; ++r) {
            const int col = kbase + 32 + (r & 3) + 8 * (r >> 2);
            float x = acc1[r];
            if (col == ig.x || col == ig.y || col == ig.z || col == ig.w)
                x = -INFINITY;
            acc1[r] = x;
            if (x > bm || (x == bm && col < bi)) { bm = x; bi = col; }
        }
        float se = 0.f;
#pragma unroll
        for (int r = 0; r < 16; ++r) se += __expf(acc0[r] - bm);
#pragma unroll
        for (int r = 0; r < 16; ++r) se += __expf(acc1[r] - bm);

        // merge with partner hi-half (same qrow, other 4-row k-groups)
        const float obm = __shfl_xor(bm, 32);
        const float ose = __shfl_xor(se, 32);
        const int   obi = __shfl_xor(bi, 32);
        const float nm = fmaxf(bm, obm);
        se = se * __expf(bm - nm) + ose * __expf(obm - nm);
        if (obm > bm || (obm == bm && obi < bi)) bi = obi;
        bm = nm;
        if (hi == 0)
            part[(size_t)qrow * NCHUNK + bx] =
                make_float4(bm, se, __int_as_float(bi), 0.f);
    }
}

// ---------------------------------------------------------------------------
// Kernel B: 4 rows per 256-thread block (one wave per row).  Merge 128
// chunk partials (serial merge of l and l+64, then xor-reduce) -> lse +
// argmax; positives recomputed EXACTLY in fp32 (coalesced row-gather).
// ---------------------------------------------------------------------------
__global__ __launch_bounds__(256)
void combine_kernel(const float4* __restrict__ part,
                    const float* __restrict__ Q, const float* __restrict__ K,
                    const int* __restrict__ pos,
                    float* __restrict__ logp, float* __restrict__ corrects)
{
    const int row = blockIdx.x * 4 + (threadIdx.x >> 6);
    const int lane = threadIdx.x & 63;

    float4 p0 = part[(size_t)row * NCHUNK + lane];
    float m = p0.x, s = p0.y, av = p0.x;
    int ai = __float_as_int(p0.z);
    {
        float4 p = part[(size_t)row * NCHUNK + 64 + lane];
        int oi = __float_as_int(p.z);
        float nm = fmaxf(m, p.x);
        s = s * __expf(m - nm) + p.y * __expf(p.x - nm);
        m = nm;
        if (p.x > av || (p.x == av && oi < ai)) { av = p.x; ai = oi; }
    }

#pragma unroll
    for (int off = 32; off >= 1; off >>= 1) {
        float om = __shfl_xor(m, off);
        float os = __shfl_xor(s, off);
        float oav = __shfl_xor(av, off);
        int oi = __shfl_xor(ai, off);
        float nm = fmaxf(m, om);
        s = s * __expf(m - nm) + os * __expf(om - nm);
        m = nm;
        if (oav > av || (oav == av && oi < ai)) { av = oav; ai = oi; }
    }
    float lse = m + __logf(s);

    int pi[4];
#pragma unroll
    for (int p = 0; p < 4; ++p) pi[p] = pos[row * P_IDX + p];

    // positive dot-products in exact fp32: lane covers 8 consecutive d-elements
    const float4* q4 = (const float4*)(Q + (size_t)row * D_DIM);
    float4 qa = q4[lane * 2], qb = q4[lane * 2 + 1];
    float d[4];
#pragma unroll
    for (int p = 0; p < 4; ++p) {
        const float4* k4 = (const float4*)(K + (size_t)pi[p] * D_DIM);
        float4 ka = k4[lane * 2], kb = k4[lane * 2 + 1];
        d[p] = qa.x * ka.x + qa.y * ka.y + qa.z * ka.z + qa.w * ka.w
             + qb.x * kb.x + qb.y * kb.y + qb.z * kb.z + qb.w * kb.w;
    }
#pragma unroll
    for (int off = 32; off >= 1; off >>= 1) {
#pragma unroll
        for (int p = 0; p < 4; ++p) d[p] += __shfl_xor(d[p], off);
    }

    if (lane == 0) {
        float ps[4];
#pragma unroll
        for (int p = 0; p < 4; ++p) ps[p] = d[p] * INV_TEMP;
        const bool v1 = (pi[1] != pi[0]);
        const bool v2 = (pi[2] != pi[0]) && (pi[2] != pi[1]);
        const bool v3 = (pi[3] != pi[0]) && (pi[3] != pi[1]) && (pi[3] != pi[2]);
        float pm = ps[0];
        if (v1) pm = fmaxf(pm, ps[1]);
        if (v2) pm = fmaxf(pm, ps[2]);
        if (v3) pm = fmaxf(pm, ps[3]);
        float pse = __expf(ps[0] - pm);
        if (v1) pse += __expf(ps[1] - pm);
        if (v2) pse += __expf(ps[2] - pm);
        if (v3) pse += __expf(ps[3] - pm);
        float pos_lse = pm + __logf(pse);
        logp[row] = pos_lse - lse;
        bool corr = (ai == pi[0]) || (ai == pi[1]) || (ai == pi[2]) || (ai == pi[3]);
        corrects[row] = corr ? 1.0f : 0.0f;
    }
}

// ---------------------------------------------------------------------------
// Kernel C: deterministic fixed-order reduction of logp -> loss
// ---------------------------------------------------------------------------
__global__ __launch_bounds__(256)
void loss_kernel(const float* __restrict__ logp, float* __restrict__ out)
{
    __shared__ float sm[256];
    const int t = threadIdx.x;
    float s = 0.f;
    for (int i = t; i < N_Q; i += 256) s += logp[i];
    sm[t] = s;
    __syncthreads();
    for (int off = 128; off >= 1; off >>= 1) {
        if (t < off) sm[t] += sm[t + off];
        __syncthreads();
    }
    if (t == 0) out[0] = -sm[0];
}

// ---------------------------------------------------------------------------
extern "C" void kernel_launch(void* const* d_in, const int* in_sizes, int n_in,
                              void* d_out, int out_size, void* d_ws, size_t ws_size,
                              hipStream_t stream)
{
    const float* Q = (const float*)d_in[0];
    const float* K = (const float*)d_in[1];
    const int* pos = (const int*)d_in[2];
    const int* ign = (const int*)d_in[3];
    float* out = (float*)d_out;

    // workspace layout (total ~20 MB)
    _Float16* Qp = (_Float16*)d_ws;                              // 4 MB
    _Float16* Kp = Qp + (size_t)N_Q * D_DIM;                     // 8 MB
    float4* part = (float4*)(Kp + (size_t)M_K * D_DIM);          // 8 MB
    float* logp = (float*)(part + (size_t)N_Q * NCHUNK);         // 16 KB

    const int qunits = N_Q / 32 * 32;     // 4096
    const int totunits = qunits + M_K / 32 * 32;   // 12288
    pack_f16<<<totunits / 4, 256, 0, stream>>>(Q, K, Qp, Kp, qunits, totunits);

    dim3 gridA(M_K / 64, 8);   // 128 kTiles x 8 by-slices
    scores_mfma<<<gridA, 256, 0, stream>>>(Qp, Kp, ign, part);
    combine_kernel<<<N_Q / 4, 256, 0, stream>>>(part, Q, K, pos, logp, out + 1);
    loss_kernel<<<1, 256, 0, stream>>>(logp, out);
}

// Round 24
// 73.252 us; speedup vs baseline: 1.0879x; 1.0879x over previous
//
#include <hip/hip_runtime.h>
#include <math.h>

// Problem constants (from reference)
#define N_Q 4096
#define M_K 8192
#define D_DIM 512
#define P_IDX 4
#define INV_TEMP 10.0f

#define NCHUNK 64           // 8192 cols / 128-col (interleaved) merged chunks

typedef __attribute__((ext_vector_type(8))) _Float16 f16x8;
typedef __attribute__((ext_vector_type(16))) float f32x16;

// ---------------------------------------------------------------------------
// Pack fp32 row-major [nrows][512] into MFMA-fragment-ordered fp16 (Q and K
// fused in one launch; Q pre-scaled by INV_TEMP).
// A wave's 32x32x16 fragment for (rb, ks) is the contiguous 1 KB at chunk
// (rb*32+ks)*64 + lane -> perfectly coalesced stream.
// ---------------------------------------------------------------------------
__global__ __launch_bounds__(256)
void pack_f16(const float* __restrict__ Q, const float* __restrict__ K,
              _Float16* __restrict__ Pq, _Float16* __restrict__ Pk,
              int qunits, int totunits)
{
    const int wunit = blockIdx.x * 4 + (threadIdx.x >> 6);
    if (wunit >= totunits) return;
    const bool isq = (wunit < qunits);
    const int u = isq ? wunit : wunit - qunits;
    const float* X = isq ? Q : K;
    _Float16* P = isq ? Pq : Pk;
    const float scale = isq ? INV_TEMP : 1.0f;
    const int rb = u >> 5, ks = u & 31;
    const int lane = threadIdx.x & 63;
    const int hi = lane >> 5, lx = lane & 31;
    const int row = rb * 32 + lx;
    const float4* src = (const float4*)(X + (size_t)row * D_DIM + ks * 16 + hi * 8);
    float4 v0 = src[0], v1 = src[1];
    f16x8 o;
    o[0] = (_Float16)(v0.x * scale); o[1] = (_Float16)(v0.y * scale);
    o[2] = (_Float16)(v0.z * scale); o[3] = (_Float16)(v0.w * scale);
    o[4] = (_Float16)(v1.x * scale); o[5] = (_Float16)(v1.y * scale);
    o[6] = (_Float16)(v1.z * scale); o[7] = (_Float16)(v1.w * scale);
    ((f16x8*)P)[(size_t)u * 64 + lane] = o;
}

// ---------------------------------------------------------------------------
// LDS-free, barrier-free swapped fp16 MFMA GEMM: scores^T = MFMA(K, Q).
// Depth-4 rotating pipeline (R15-verified optimum): 4 fragment sets R/S/T/U
// in flight; set s consumed at step ks, reloaded for ks+4; no copies,
// counted vmcnt by compiler; setprio around MFMA quartets.
// Epilogue: in-lane {mask,max,argmax,sumexp} -> shfl_xor(32) hi-merge
// (R18-verified) -> cross-wr merge via 2 KB LDS + one barrier -> one
// 128-col chunk partial per qrow per block (NCHUNK=64, part = 4 MB).
// 128(K) x 128(Q) tile, 4 waves (2 wr x 2 wc), acc[2][2] f32x16.
// Grid (64 kTiles, 32 qTiles), block 256.
// ---------------------------------------------------------------------------
#define MFMA_QUARTET(A0, A1, B0, B1)                                            \
    __builtin_amdgcn_s_setprio(1);                                              \
    acc[0][0] = __builtin_amdgcn_mfma_f32_32x32x16_f16(A0, B0, acc[0][0], 0, 0, 0); \
    acc[0][1] = __builtin_amdgcn_mfma_f32_32x32x16_f16(A0, B1, acc[0][1], 0, 0, 0); \
    acc[1][0] = __builtin_amdgcn_mfma_f32_32x32x16_f16(A1, B0, acc[1][0], 0, 0, 0); \
    acc[1][1] = __builtin_amdgcn_mfma_f32_32x32x16_f16(A1, B1, acc[1][1], 0, 0, 0); \
    __builtin_amdgcn_s_setprio(0);

__global__ __launch_bounds__(256)
void scores_mfma(const _Float16* __restrict__ Qp, const _Float16* __restrict__ Kp,
                 const int* __restrict__ ign, float4* __restrict__ part)
{
    __shared__ float4 mrg[2][2][32];      // [wc][j][lx] partials from wr=0

    const int tid = threadIdx.x;          // 0..255
    const int lane = tid & 63;
    const int wave = tid >> 6;            // 0..3
    const int wr = wave >> 1, wc = wave & 1;
    const int hi = lane >> 5, lx = lane & 31;
    const int bx = blockIdx.x;            // K-tile (128 rows), 0..63
    const int by = blockIdx.y;            // Q-tile (128 rows), 0..31

    const f16x8* Kp8 = (const f16x8*)Kp;
    const f16x8* Qp8 = (const f16x8*)Qp;
    const f16x8* A0p = Kp8 + ((size_t)(bx * 4 + wr * 2 + 0) * 32) * 64 + lane;
    const f16x8* A1p = Kp8 + ((size_t)(bx * 4 + wr * 2 + 1) * 32) * 64 + lane;
    const f16x8* B0p = Qp8 + ((size_t)(by * 4 + wc * 2 + 0) * 32) * 64 + lane;
    const f16x8* B1p = Qp8 + ((size_t)(by * 4 + wc * 2 + 1) * 32) * 64 + lane;

    f32x16 acc[2][2];
#pragma unroll
    for (int i = 0; i < 2; ++i)
#pragma unroll
        for (int j = 0; j < 2; ++j) acc[i][j] = (f32x16)0.f;

    // prologue: sets for ks = 0 (R), 1 (S), 2 (T), 3 (U)
    f16x8 rA0 = A0p[0],   rA1 = A1p[0],   rB0 = B0p[0],   rB1 = B1p[0];
    f16x8 sA0 = A0p[64],  sA1 = A1p[64],  sB0 = B0p[64],  sB1 = B1p[64];
    f16x8 tA0 = A0p[128], tA1 = A1p[128], tB0 = B0p[128], tB1 = B1p[128];
    f16x8 uA0 = A0p[192], uA1 = A1p[192], uB0 = B0p[192], uB1 = B1p[192];

    for (int ks = 0; ks < 32; ks += 4) {
        MFMA_QUARTET(rA0, rA1, rB0, rB1)
        if (ks + 4 < 32) {
            const int o = (ks + 4) * 64;
            rA0 = A0p[o]; rA1 = A1p[o]; rB0 = B0p[o]; rB1 = B1p[o];
        }
        MFMA_QUARTET(sA0, sA1, sB0, sB1)
        if (ks + 5 < 32) {
            const int o = (ks + 5) * 64;
            sA0 = A0p[o]; sA1 = A1p[o]; sB0 = B0p[o]; sB1 = B1p[o];
        }
        MFMA_QUARTET(tA0, tA1, tB0, tB1)
        if (ks + 6 < 32) {
            const int o = (ks + 6) * 64;
            tA0 = A0p[o]; tA1 = A1p[o]; tB0 = B0p[o]; tB1 = B1p[o];
        }
        MFMA_QUARTET(uA0, uA1, uB0, uB1)
        if (ks + 7 < 32) {
            const int o = (ks + 7) * 64;
            uA0 = A0p[o]; uA1 = A1p[o]; uB0 = B0p[o]; uB1 = B1p[o];
        }
    }

    // Epilogue:
    //   acc[i][j][r] = score(qrow = by*128 + wc*64 + j*32 + lx,
    //                        kcol = bx*128 + wr*64 + i*32 + (r&3)+8*(r>>2)+4*hi)
    // Step 1 (in-lane + hi-merge, R18-verified): per j -> 64-col partial.
    const int kbase = bx * 128 + wr * 64 + 4 * hi;
    float bmj[2], sej[2]; int bij[2];
#pragma unroll
    for (int j = 0; j < 2; ++j) {
        const int qrow = by * 128 + wc * 64 + j * 32 + lx;
        const int4 ig = ((const int4*)ign)[qrow];   // 4 ignore indices, 16B
        float bm = -INFINITY; int bi = 0x7fffffff;
#pragma unroll
        for (int i = 0; i < 2; ++i) {
#pragma unroll
            for (int r = 0; r < 16; ++r) {
                const int col = kbase + i * 32 + (r & 3) + 8 * (r >> 2);
                float x = acc[i][j][r];
                if (col == ig.x || col == ig.y || col == ig.z || col == ig.w)
                    x = -INFINITY;
                acc[i][j][r] = x;
                if (x > bm || (x == bm && col < bi)) { bm = x; bi = col; }
            }
        }
        float se = 0.f;
#pragma unroll
        for (int i = 0; i < 2; ++i)
#pragma unroll
            for (int r = 0; r < 16; ++r)
                se += __expf(acc[i][j][r] - bm);

        // merge with partner hi-half (same qrow, other 32 k-cols)
        const float obm = __shfl_xor(bm, 32);
        const float ose = __shfl_xor(se, 32);
        const int   obi = __shfl_xor(bi, 32);
        const float nm = fmaxf(bm, obm);
        se = se * __expf(bm - nm) + ose * __expf(obm - nm);
        if (obm > bm || (obm == bm && obi < bi)) bi = obi;
        bm = nm;
        bmj[j] = bm; sej[j] = se; bij[j] = bi;
    }

    // Step 2: cross-wr merge via LDS (wr=0 posts, wr=1 merges+writes).
    if (wr == 0 && hi == 0) {
#pragma unroll
        for (int j = 0; j < 2; ++j)
            mrg[wc][j][lx] = make_float4(bmj[j], sej[j], __int_as_float(bij[j]), 0.f);
    }
    __syncthreads();
    if (wr == 1 && hi == 0) {
#pragma unroll
        for (int j = 0; j < 2; ++j) {
            const float4 o = mrg[wc][j][lx];
            const int   obi = __float_as_int(o.z);
            float bm = bmj[j], se = sej[j]; int bi = bij[j];
            const float nm = fmaxf(bm, o.x);
            se = se * __expf(bm - nm) + o.y * __expf(o.x - nm);
            if (o.x > bm || (o.x == bm && obi < bi)) bi = obi;
            bm = nm;
            const int qrow = by * 128 + wc * 64 + j * 32 + lx;
            part[(size_t)qrow * NCHUNK + bx] =
                make_float4(bm, se, __int_as_float(bi), 0.f);
        }
    }
}

// ---------------------------------------------------------------------------
// Kernel B: 4 rows per 256-thread block (one wave per row).  Merge 64
// chunk partials (one load per lane) -> lse + argmax; positives recomputed
// EXACTLY in fp32 (coalesced row-gather: lane l reads bytes [8l, 8l+8) of
// each row -> one transaction per row).  Fast-math __expf/__logf.
// ---------------------------------------------------------------------------
__global__ __launch_bounds__(256)
void combine_kernel(const float4* __restrict__ part,
                    const float* __restrict__ Q, const float* __restrict__ K,
                    const int* __restrict__ pos,
                    float* __restrict__ logp, float* __restrict__ corrects)
{
    const int row = blockIdx.x * 4 + (threadIdx.x >> 6);
    const int lane = threadIdx.x & 63;

    float4 p0 = part[(size_t)row * NCHUNK + lane];
    float m = p0.x, s = p0.y, av = p0.x;
    int ai = __float_as_int(p0.z);

#pragma unroll
    for (int off = 32; off >= 1; off >>= 1) {
        float om = __shfl_xor(m, off);
        float os = __shfl_xor(s, off);
        float oav = __shfl_xor(av, off);
        int oi = __shfl_xor(ai, off);
        float nm = fmaxf(m, om);
        s = s * __expf(m - nm) + os * __expf(om - nm);
        m = nm;
        if (oav > av || (oav == av && oi < ai)) { av = oav; ai = oi; }
    }
    float lse = m + __logf(s);

    int pi[4];
#pragma unroll
    for (int p = 0; p < 4; ++p) pi[p] = pos[row * P_IDX + p];

    // positive dot-products in exact fp32: lane covers 8 consecutive d-elements
    const float4* q4 = (const float4*)(Q + (size_t)row * D_DIM);
    float4 qa = q4[lane * 2], qb = q4[lane * 2 + 1];
    float d[4];
#pragma unroll
    for (int p = 0; p < 4; ++p) {
        const float4* k4 = (const float4*)(K + (size_t)pi[p] * D_DIM);
        float4 ka = k4[lane * 2], kb = k4[lane * 2 + 1];
        d[p] = qa.x * ka.x + qa.y * ka.y + qa.z * ka.z + qa.w * ka.w
             + qb.x * kb.x + qb.y * kb.y + qb.z * kb.z + qb.w * kb.w;
    }
#pragma unroll
    for (int off = 32; off >= 1; off >>= 1) {
#pragma unroll
        for (int p = 0; p < 4; ++p) d[p] += __shfl_xor(d[p], off);
    }

    if (lane == 0) {
        float ps[4];
#pragma unroll
        for (int p = 0; p < 4; ++p) ps[p] = d[p] * INV_TEMP;
        const bool v1 = (pi[1] != pi[0]);
        const bool v2 = (pi[2] != pi[0]) && (pi[2] != pi[1]);
        const bool v3 = (pi[3] != pi[0]) && (pi[3] != pi[1]) && (pi[3] != pi[2]);
        float pm = ps[0];
        if (v1) pm = fmaxf(pm, ps[1]);
        if (v2) pm = fmaxf(pm, ps[2]);
        if (v3) pm = fmaxf(pm, ps[3]);
        float pse = __expf(ps[0] - pm);
        if (v1) pse += __expf(ps[1] - pm);
        if (v2) pse += __expf(ps[2] - pm);
        if (v3) pse += __expf(ps[3] - pm);
        float pos_lse = pm + __logf(pse);
        logp[row] = pos_lse - lse;
        bool corr = (ai == pi[0]) || (ai == pi[1]) || (ai == pi[2]) || (ai == pi[3]);
        corrects[row] = corr ? 1.0f : 0.0f;
    }
}

// ---------------------------------------------------------------------------
// Kernel C: deterministic fixed-order reduction of logp -> loss
// ---------------------------------------------------------------------------
__global__ __launch_bounds__(256)
void loss_kernel(const float* __restrict__ logp, float* __restrict__ out)
{
    __shared__ float sm[256];
    const int t = threadIdx.x;
    float s = 0.f;
    for (int i = t; i < N_Q; i += 256) s += logp[i];
    sm[t] = s;
    __syncthreads();
    for (int off = 128; off >= 1; off >>= 1) {
        if (t < off) sm[t] += sm[t + off];
        __syncthreads();
    }
    if (t == 0) out[0] = -sm[0];
}

// ---------------------------------------------------------------------------
extern "C" void kernel_launch(void* const* d_in, const int* in_sizes, int n_in,
                              void* d_out, int out_size, void* d_ws, size_t ws_size,
                              hipStream_t stream)
{
    const float* Q = (const float*)d_in[0];
    const float* K = (const float*)d_in[1];
    const int* pos = (const int*)d_in[2];
    const int* ign = (const int*)d_in[3];
    float* out = (float*)d_out;

    // workspace layout (total ~16 MB)
    _Float16* Qp = (_Float16*)d_ws;                              // 4 MB
    _Float16* Kp = Qp + (size_t)N_Q * D_DIM;                     // 8 MB
    float4* part = (float4*)(Kp + (size_t)M_K * D_DIM);          // 4 MB
    float* logp = (float*)(part + (size_t)N_Q * NCHUNK);         // 16 KB

    const int qunits = N_Q / 32 * 32;     // 4096
    const int totunits = qunits + M_K / 32 * 32;   // 12288
    pack_f16<<<totunits / 4, 256, 0, stream>>>(Q, K, Qp, Kp, qunits, totunits);

    dim3 gridA(M_K / 128, N_Q / 128);   // 64 kTiles x 32 qTiles
    scores_mfma<<<gridA, 256, 0, stream>>>(Qp, Kp, ign, part);
    combine_kernel<<<N_Q / 4, 256, 0, stream>>>(part, Q, K, pos, logp, out + 1);
    loss_kernel<<<1, 256, 0, stream>>>(logp, out);
}